// Round 1
// baseline (866.691 us; speedup 1.0000x reference)
//
#include <hip/hip_runtime.h>
#include <stdint.h>

#define N_PIX 401408
#define HWIMG 12544   // 112*112
#define LN_EPS 1e-5f

// ---------------- workspace layout ----------------
struct Ws {
  double R[3][8];          // sinkhorn row sums per iter, [iter][c*2+m]
  float  u1[8];            // u after iter1 row-norm
  float  u2[8];
  float  u3[8];
  unsigned cnt4[4];        // class pixel counts (Bn)
  unsigned nmk[8];         // correct counts per (c,m)
  float  protoN[8][256];   // l2-normalized prototypes, row r = c*2+m
  float  fAcc[8][256];     // f accumulator
  unsigned char flags[N_PIX];  // correct flag per pixel
};

// ---------------- wave reductions ----------------
__device__ __forceinline__ float wredf(float v) {
#pragma unroll
  for (int o = 32; o > 0; o >>= 1) v += __shfl_xor(v, o, 64);
  return v;
}
__device__ __forceinline__ double wredd(double v) {
#pragma unroll
  for (int o = 32; o > 0; o >>= 1) v += __shfl_xor(v, o, 64);
  return v;
}
__device__ __forceinline__ unsigned wredu(unsigned v) {
#pragma unroll
  for (int o = 32; o > 0; o >>= 1) v += (unsigned)__shfl_xor((int)v, o, 64);
  return v;
}

// ---------------- K0: init ws + normalize prototypes ----------------
__global__ __launch_bounds__(512) void k_init(const float* __restrict__ protos, Ws* __restrict__ ws) {
  int tid = threadIdx.x;
  if (tid < 24) ((double*)ws->R)[tid] = 0.0;
  if (tid < 8) { ws->u1[tid] = 0.f; ws->u2[tid] = 0.f; ws->u3[tid] = 0.f; ws->nmk[tid] = 0u; }
  if (tid < 4) ws->cnt4[tid] = 0u;
  float* fa = &ws->fAcc[0][0];
  for (int i = tid; i < 8 * 256; i += 512) fa[i] = 0.f;

  int r = tid >> 6, lane = tid & 63;
  const float4 p = *(const float4*)(protos + r * 256 + lane * 4);
  float ss = p.x * p.x + p.y * p.y + p.z * p.z + p.w * p.w;
  ss = wredf(ss);
  float inv = 1.0f / fmaxf(sqrtf(ss), 1e-12f);
  float4 o; o.x = p.x * inv; o.y = p.y * inv; o.z = p.z * inv; o.w = p.w * inv;
  *(float4*)(&ws->protoN[r][lane * 4]) = o;
}

// ---------------- K1: per-pixel main ----------------
// one wave per pixel; block = 4 waves
__global__ __launch_bounds__(256) void k_main(
    const float* __restrict__ X, const int* __restrict__ label,
    const float* __restrict__ fng, const float* __restrict__ fnb,
    const float* __restrict__ mng, const float* __restrict__ mnb,
    Ws* __restrict__ ws,
    float* __restrict__ out_nearest, float* __restrict__ out_logits) {
  __shared__ float pr[8 * 256];
  int tid = threadIdx.x;
#pragma unroll
  for (int i = tid; i < 2048; i += 256) pr[i] = (&ws->protoN[0][0])[i];
  __syncthreads();

  int wave = tid >> 6, lane = tid & 63;
  int n = blockIdx.x * 4 + wave;

  const float4 x = *(const float4*)(X + (size_t)n * 256 + lane * 4);
  float s = x.x + x.y + x.z + x.w;
  float q = x.x * x.x + x.y * x.y + x.z * x.z + x.w * x.w;
  s = wredf(s); q = wredf(q);
  float mu = s * (1.0f / 256.0f);
  float var = q * (1.0f / 256.0f) - mu * mu;
  float rstd = rsqrtf(var + LN_EPS);
  const float4 g = *(const float4*)(fng + lane * 4);
  const float4 b = *(const float4*)(fnb + lane * 4);
  float y0 = (x.x - mu) * rstd * g.x + b.x;
  float y1 = (x.y - mu) * rstd * g.y + b.y;
  float y2 = (x.z - mu) * rstd * g.z + b.z;
  float y3 = (x.w - mu) * rstd * g.w + b.w;
  float qq = y0 * y0 + y1 * y1 + y2 * y2 + y3 * y3;
  qq = wredf(qq);
  float inv = 1.0f / fmaxf(sqrtf(qq), 1e-12f);
  y0 *= inv; y1 *= inv; y2 *= inv; y3 *= inv;

  float dot[8];
#pragma unroll
  for (int j = 0; j < 8; j++) {
    const float4 pv = *(const float4*)(&pr[j * 256 + lane * 4]);
    dot[j] = y0 * pv.x + y1 * pv.y + y2 * pv.z + y3 * pv.w;
  }
#pragma unroll
  for (int o = 32; o > 0; o >>= 1) {
#pragma unroll
    for (int j = 0; j < 8; j++) dot[j] += __shfl_xor(dot[j], o, 64);
  }

  if (lane == 0) {
    float* lg = out_logits + (size_t)n * 8;
#pragma unroll
    for (int k = 0; k < 4; k++) { lg[k] = dot[k * 2]; lg[4 + k] = dot[k * 2 + 1]; }
    float nr[4];
#pragma unroll
    for (int k = 0; k < 4; k++) nr[k] = fmaxf(dot[k * 2], dot[k * 2 + 1]);
    float m4 = 0.25f * (nr[0] + nr[1] + nr[2] + nr[3]);
    float v4 = 0.25f * (nr[0] * nr[0] + nr[1] * nr[1] + nr[2] * nr[2] + nr[3] * nr[3]) - m4 * m4;
    float rs4 = rsqrtf(v4 + LN_EPS);
    int bimg = n / HWIMG;
    int p = n - bimg * HWIMG;
    float best = -3.4e38f; int pred = 0;
#pragma unroll
    for (int k = 0; k < 4; k++) {
      float lnv = (nr[k] - m4) * rs4 * mng[k] + mnb[k];
      out_nearest[((size_t)bimg * 4 + k) * HWIMG + p] = lnv;
      if (lnv > best) { best = lnv; pred = k; }
    }
    ws->flags[n] = (label[n] == pred) ? (unsigned char)1 : (unsigned char)0;
  }
}

// ---------------- K2: sinkhorn reduction pass (iter = 1..3) ----------------
template <int ITER>
__global__ __launch_bounds__(256) void k_sink(const float* __restrict__ logits,
                                              const int* __restrict__ label,
                                              Ws* __restrict__ ws) {
  __shared__ float su1[8], su2[8], sBn[4];
  int tid = threadIdx.x;
  if (ITER >= 2) {
    if (tid < 8) su1[tid] = ws->u1[tid];
    if (ITER >= 3 && tid < 8) su2[tid] = ws->u2[tid];
    if (tid < 4) sBn[tid] = fmaxf((float)ws->cnt4[tid], 1.0f);
  }
  __syncthreads();

  double a0 = 0, a1 = 0, a2 = 0, a3 = 0, a4 = 0, a5 = 0, a6 = 0, a7 = 0;
  unsigned c0 = 0, c1 = 0, c2 = 0, c3 = 0;
  int gtid = blockIdx.x * 256 + tid;
  int T = gridDim.x * 256;
  for (int n = gtid; n < N_PIX; n += T) {
    int c = label[n];
    const float4 la = *(const float4*)(logits + (size_t)n * 8);
    const float4 lb = *(const float4*)(logits + (size_t)n * 8 + 4);
    float s0 = (c & 2) ? ((c & 1) ? la.w : la.z) : ((c & 1) ? la.y : la.x);
    float s1 = (c & 2) ? ((c & 1) ? lb.w : lb.z) : ((c & 1) ? lb.y : lb.x);
    float E0 = expf(s0 / 0.05f);
    float E1 = expf(s1 / 0.05f);
    float v = 1.0f;
    if (ITER >= 2) {
      float S1 = su1[c * 2] * E0 + su1[c * 2 + 1] * E1;
      float v1 = 1.0f / (fmaxf(S1, 1e-30f) * sBn[c]);
      v = v1;
      if (ITER >= 3) {
        float S2 = su2[c * 2] * E0 + su2[c * 2 + 1] * E1;
        v = v1 / (fmaxf(v1 * S2, 1e-30f) * sBn[c]);
      }
    }
    double t0 = (double)(v * E0), t1 = (double)(v * E1);
    if (c == 0) { a0 += t0; a1 += t1; c0++; }
    else if (c == 1) { a2 += t0; a3 += t1; c1++; }
    else if (c == 2) { a4 += t0; a5 += t1; c2++; }
    else { a6 += t0; a7 += t1; c3++; }
  }
  a0 = wredd(a0); a1 = wredd(a1); a2 = wredd(a2); a3 = wredd(a3);
  a4 = wredd(a4); a5 = wredd(a5); a6 = wredd(a6); a7 = wredd(a7);
  __shared__ double lds[4][8];
  __shared__ unsigned ldc[4][4];
  int wave = tid >> 6, lane = tid & 63;
  if (ITER == 1) { c0 = wredu(c0); c1 = wredu(c1); c2 = wredu(c2); c3 = wredu(c3); }
  if (lane == 0) {
    lds[wave][0] = a0; lds[wave][1] = a1; lds[wave][2] = a2; lds[wave][3] = a3;
    lds[wave][4] = a4; lds[wave][5] = a5; lds[wave][6] = a6; lds[wave][7] = a7;
    if (ITER == 1) { ldc[wave][0] = c0; ldc[wave][1] = c1; ldc[wave][2] = c2; ldc[wave][3] = c3; }
  }
  __syncthreads();
  if (tid < 8) {
    double ssum = lds[0][tid] + lds[1][tid] + lds[2][tid] + lds[3][tid];
    unsafeAtomicAdd(&ws->R[ITER - 1][tid], ssum);
  }
  if (ITER == 1 && tid < 4) {
    unsigned cs = ldc[0][tid] + ldc[1][tid] + ldc[2][tid] + ldc[3][tid];
    atomicAdd(&ws->cnt4[tid], cs);
  }
}

// ---------------- Ku: tiny u update ----------------
template <int ITER>
__global__ void k_u(Ws* __restrict__ ws) {
  int j = threadIdx.x;
  if (j >= 8) return;
  float R = (float)ws->R[ITER - 1][j];
  if (ITER == 1) {
    int c = j >> 1;
    float S = (float)ws->R[0][c * 2] + (float)ws->R[0][c * 2 + 1];
    float u0 = 1.0f / fmaxf(S, 1e-30f);
    ws->u1[j] = u0 / (fmaxf(u0 * R, 1e-30f) * 2.0f);
  } else if (ITER == 2) {
    float up = ws->u1[j];
    ws->u2[j] = up / (fmaxf(up * R, 1e-30f) * 2.0f);
  } else {
    float up = ws->u2[j];
    ws->u3[j] = up / (fmaxf(up * R, 1e-30f) * 2.0f);
  }
}

// ---------------- K3: proto_target + f / count accumulation ----------------
__global__ __launch_bounds__(256) void k_accum(
    const float* __restrict__ X, const int* __restrict__ label,
    const float* __restrict__ fng, const float* __restrict__ fnb,
    const float* __restrict__ logits, Ws* __restrict__ ws,
    float* __restrict__ out_target) {
  __shared__ float fa[4 * 2048];  // per-wave f accumulator copies (32 KB)
  __shared__ float su[8];
  __shared__ unsigned ldc[4][8];
  int tid = threadIdx.x;
  if (tid < 8) su[tid] = ws->u3[tid];
  for (int i = tid; i < 4 * 2048; i += 256) fa[i] = 0.f;
  __syncthreads();

  int wave = tid >> 6, lane = tid & 63;
  const float4 g4 = *(const float4*)(fng + lane * 4);
  const float4 b4 = *(const float4*)(fnb + lane * 4);
  float* myAcc = &fa[wave * 2048];

  unsigned cl[8] = {0, 0, 0, 0, 0, 0, 0, 0};
  int gw = blockIdx.x * 4 + wave;
  int GW = gridDim.x * 4;
  for (int ch = gw; ch < N_PIX / 64; ch += GW) {
    int n = ch * 64 + lane;
    int c = label[n];
    int fl = ws->flags[n];
    float s0 = logits[(size_t)n * 8 + c];
    float s1 = logits[(size_t)n * 8 + 4 + c];
    float E0 = expf(s0 / 0.05f);
    float E1 = expf(s1 / 0.05f);
    int idx = (su[c * 2 + 1] * E1 > su[c * 2] * E0) ? 1 : 0;
    out_target[n] = (float)(idx + 2 * c);
    int bucket = c * 2 + idx;
#pragma unroll
    for (int j = 0; j < 8; j++) cl[j] += (fl && bucket == j) ? 1u : 0u;

    unsigned long long mask = __ballot(fl);
    while (mask) {
      int src = __builtin_ctzll(mask);
      mask &= (mask - 1);
      int cc = __shfl(c, src, 64);
      int ii = __shfl(idx, src, 64);
      int nn = ch * 64 + src;
      const float4 x = *(const float4*)(X + (size_t)nn * 256 + lane * 4);
      float s = x.x + x.y + x.z + x.w;
      float q = x.x * x.x + x.y * x.y + x.z * x.z + x.w * x.w;
      s = wredf(s); q = wredf(q);
      float mu = s * (1.0f / 256.0f);
      float var = q * (1.0f / 256.0f) - mu * mu;
      float rstd = rsqrtf(var + LN_EPS);
      float y0 = (x.x - mu) * rstd * g4.x + b4.x;
      float y1 = (x.y - mu) * rstd * g4.y + b4.y;
      float y2 = (x.z - mu) * rstd * g4.z + b4.z;
      float y3 = (x.w - mu) * rstd * g4.w + b4.w;
      float qq = y0 * y0 + y1 * y1 + y2 * y2 + y3 * y3;
      qq = wredf(qq);
      float inv = 1.0f / fmaxf(sqrtf(qq), 1e-12f);
      float* dst = myAcc + (cc * 2 + ii) * 256 + lane * 4;
      dst[0] += y0 * inv; dst[1] += y1 * inv; dst[2] += y2 * inv; dst[3] += y3 * inv;
    }
  }
#pragma unroll
  for (int j = 0; j < 8; j++) cl[j] = wredu(cl[j]);
  if (lane == 0) {
#pragma unroll
    for (int j = 0; j < 8; j++) ldc[wave][j] = cl[j];
  }
  __syncthreads();
  float* fg = &ws->fAcc[0][0];
  for (int i = tid; i < 2048; i += 256) {
    float ssum = fa[i] + fa[2048 + i] + fa[4096 + i] + fa[6144 + i];
    unsafeAtomicAdd(fg + i, ssum);
  }
  if (tid < 8) {
    unsigned cs = ldc[0][tid] + ldc[1][tid] + ldc[2][tid] + ldc[3][tid];
    if (cs) atomicAdd(&ws->nmk[tid], cs);
  }
}

// ---------------- K4: finalize prototypes ----------------
__global__ __launch_bounds__(512) void k_final(Ws* __restrict__ ws, float* __restrict__ out_protos) {
  int tid = threadIdx.x;
  int r = tid >> 6, lane = tid & 63;
  const float4 f = *(const float4*)(&ws->fAcc[r][lane * 4]);
  float ss = wredf(f.x * f.x + f.y * f.y + f.z * f.z + f.w * f.w);
  float invf = 1.0f / fmaxf(sqrtf(ss), 1e-12f);
  unsigned nr = ws->nmk[r];
  int c = r >> 1;
  unsigned tot = ws->nmk[c * 2] + ws->nmk[c * 2 + 1];
  bool cond = (tot > 0u) && (nr != 0u);
  const float4 p = *(const float4*)(&ws->protoN[r][lane * 4]);
  float u0 = cond ? 0.999f * p.x + 0.001f * (f.x * invf) : p.x;
  float u1 = cond ? 0.999f * p.y + 0.001f * (f.y * invf) : p.y;
  float u2 = cond ? 0.999f * p.z + 0.001f * (f.z * invf) : p.z;
  float u3 = cond ? 0.999f * p.w + 0.001f * (f.w * invf) : p.w;
  float ss2 = wredf(u0 * u0 + u1 * u1 + u2 * u2 + u3 * u3);
  float invn = 1.0f / fmaxf(sqrtf(ss2), 1e-12f);
  float4 o; o.x = u0 * invn; o.y = u1 * invn; o.z = u2 * invn; o.w = u3 * invn;
  *(float4*)(out_protos + r * 256 + lane * 4) = o;
}

// ---------------- launch ----------------
extern "C" void kernel_launch(void* const* d_in, const int* in_sizes, int n_in,
                              void* d_out, int out_size, void* d_ws, size_t ws_size,
                              hipStream_t stream) {
  const float* X = (const float*)d_in[0];
  const int* label = (const int*)d_in[1];
  const float* protos = (const float*)d_in[2];
  const float* fng = (const float*)d_in[3];
  const float* fnb = (const float*)d_in[4];
  const float* mng = (const float*)d_in[5];
  const float* mnb = (const float*)d_in[6];

  float* out = (float*)d_out;
  float* out_nearest = out;                        // 32*4*12544 = 1605632
  float* out_logits = out + 1605632;               // N*8 = 3211264
  float* out_target = out_logits + 3211264;        // N
  float* out_protos = out_target + N_PIX;          // 2048
  Ws* ws = (Ws*)d_ws;

  k_init<<<1, 512, 0, stream>>>(protos, ws);
  k_main<<<N_PIX / 4, 256, 0, stream>>>(X, label, fng, fnb, mng, mnb, ws, out_nearest, out_logits);
  k_sink<1><<<512, 256, 0, stream>>>(out_logits, label, ws);
  k_u<1><<<1, 64, 0, stream>>>(ws);
  k_sink<2><<<512, 256, 0, stream>>>(out_logits, label, ws);
  k_u<2><<<1, 64, 0, stream>>>(ws);
  k_sink<3><<<512, 256, 0, stream>>>(out_logits, label, ws);
  k_u<3><<<1, 64, 0, stream>>>(ws);
  k_accum<<<512, 256, 0, stream>>>(X, label, fng, fnb, out_logits, ws, out_target);
  k_final<<<1, 512, 0, stream>>>(ws, out_protos);
}

// Round 2
// 670.264 us; speedup vs baseline: 1.2931x; 1.2931x over previous
//
#include <hip/hip_runtime.h>
#include <stdint.h>

#define N_PIX 401408
#define HWIMG 12544   // 112*112
#define LN_EPS 1e-5f

// ---------------- workspace layout ----------------
struct Ws {
  double R[3][8];          // sinkhorn row sums per iter, [iter][c*2+m]
  unsigned cnt4[4];        // class pixel counts (Bn)
  unsigned nmk[8];         // correct counts per (c,m)
  float  protoN[8][256];   // l2-normalized prototypes, row r = c*2+m
  float  fAcc[8][256];     // f accumulator
  unsigned char flags[N_PIX];  // correct flag per pixel
};

// ---------------- reductions ----------------
__device__ __forceinline__ float wredf(float v) {   // full 64-lane
#pragma unroll
  for (int o = 32; o > 0; o >>= 1) v += __shfl_xor(v, o, 64);
  return v;
}
__device__ __forceinline__ float wred16(float v) {  // within 16-lane group
  v += __shfl_xor(v, 1, 64);
  v += __shfl_xor(v, 2, 64);
  v += __shfl_xor(v, 4, 64);
  v += __shfl_xor(v, 8, 64);
  return v;
}
__device__ __forceinline__ double wredd(double v) {
#pragma unroll
  for (int o = 32; o > 0; o >>= 1) v += __shfl_xor(v, o, 64);
  return v;
}
__device__ __forceinline__ unsigned wredu(unsigned v) {
#pragma unroll
  for (int o = 32; o > 0; o >>= 1) v += (unsigned)__shfl_xor((int)v, o, 64);
  return v;
}

// ---------------- K1: per-pixel main ----------------
// 16 lanes per pixel, 4 pixels per wave, 16 pixels per block.
// LDS proto layout: word  s*132 + r*16 + e   for element d = 16*s + e of row r.
// (row stride 132 => lanes s and s+8 2-way alias only, which is free)
__global__ __launch_bounds__(256) void k_main(
    const float* __restrict__ X, const int* __restrict__ label,
    const float* __restrict__ protos,
    const float* __restrict__ fng, const float* __restrict__ fnb,
    const float* __restrict__ mng, const float* __restrict__ mnb,
    Ws* __restrict__ ws,
    float* __restrict__ out_nearest, float* __restrict__ out_logits) {
  __shared__ float prS[16 * 132];
  int tid = threadIdx.x;
  int wave = tid >> 6, lane = tid & 63;

  // block 0: zero global accumulators (k_sink/k_accum/k_final consume after
  // this kernel completes; stream order gives cross-XCD visibility)
  if (blockIdx.x == 0) {
    if (tid < 24) ((double*)ws->R)[tid] = 0.0;
    if (tid >= 24 && tid < 32) ws->nmk[tid - 24] = 0u;
    if (tid >= 32 && tid < 36) ws->cnt4[tid - 32] = 0u;
    for (int i = tid; i < 2048; i += 256) (&ws->fAcc[0][0])[i] = 0.f;
  }

  // normalize prototypes into swizzled LDS (each wave does rows w, w+4)
#pragma unroll
  for (int t = 0; t < 2; t++) {
    int r = wave + t * 4;
    const float4 p = *(const float4*)(protos + r * 256 + lane * 4);
    float ss = p.x * p.x + p.y * p.y + p.z * p.z + p.w * p.w;
    ss = wredf(ss);
    float inv = 1.0f / fmaxf(sqrtf(ss), 1e-12f);
    float4 o; o.x = p.x * inv; o.y = p.y * inv; o.z = p.z * inv; o.w = p.w * inv;
    int sd = lane >> 2;
    *(float4*)(&prS[sd * 132 + r * 16 + (lane & 3) * 4]) = o;
    if (blockIdx.x == 0) *(float4*)(&ws->protoN[r][lane * 4]) = o;
  }
  __syncthreads();

  int grp = lane >> 4, s = lane & 15;
  int n = blockIdx.x * 16 + wave * 4 + grp;

  const float* xb = X + (size_t)n * 256 + s * 16;
  const float4 x0 = *(const float4*)(xb);
  const float4 x1 = *(const float4*)(xb + 4);
  const float4 x2 = *(const float4*)(xb + 8);
  const float4 x3 = *(const float4*)(xb + 12);
  int lab = label[n];

  float sm = (x0.x + x0.y + x0.z + x0.w) + (x1.x + x1.y + x1.z + x1.w) +
             (x2.x + x2.y + x2.z + x2.w) + (x3.x + x3.y + x3.z + x3.w);
  float q = x0.x * x0.x + x0.y * x0.y + x0.z * x0.z + x0.w * x0.w +
            x1.x * x1.x + x1.y * x1.y + x1.z * x1.z + x1.w * x1.w +
            x2.x * x2.x + x2.y * x2.y + x2.z * x2.z + x2.w * x2.w +
            x3.x * x3.x + x3.y * x3.y + x3.z * x3.z + x3.w * x3.w;
  sm = wred16(sm); q = wred16(q);
  float mu = sm * (1.0f / 256.0f);
  float var = q * (1.0f / 256.0f) - mu * mu;
  float rstd = rsqrtf(var + LN_EPS);

  const float* gb = fng + s * 16;
  const float* bb = fnb + s * 16;
  const float4 g0 = *(const float4*)(gb);
  const float4 g1 = *(const float4*)(gb + 4);
  const float4 g2 = *(const float4*)(gb + 8);
  const float4 g3 = *(const float4*)(gb + 12);
  const float4 b0 = *(const float4*)(bb);
  const float4 b1 = *(const float4*)(bb + 4);
  const float4 b2 = *(const float4*)(bb + 8);
  const float4 b3 = *(const float4*)(bb + 12);

  float4 y0, y1, y2, y3;
  y0.x = (x0.x - mu) * rstd * g0.x + b0.x; y0.y = (x0.y - mu) * rstd * g0.y + b0.y;
  y0.z = (x0.z - mu) * rstd * g0.z + b0.z; y0.w = (x0.w - mu) * rstd * g0.w + b0.w;
  y1.x = (x1.x - mu) * rstd * g1.x + b1.x; y1.y = (x1.y - mu) * rstd * g1.y + b1.y;
  y1.z = (x1.z - mu) * rstd * g1.z + b1.z; y1.w = (x1.w - mu) * rstd * g1.w + b1.w;
  y2.x = (x2.x - mu) * rstd * g2.x + b2.x; y2.y = (x2.y - mu) * rstd * g2.y + b2.y;
  y2.z = (x2.z - mu) * rstd * g2.z + b2.z; y2.w = (x2.w - mu) * rstd * g2.w + b2.w;
  y3.x = (x3.x - mu) * rstd * g3.x + b3.x; y3.y = (x3.y - mu) * rstd * g3.y + b3.y;
  y3.z = (x3.z - mu) * rstd * g3.z + b3.z; y3.w = (x3.w - mu) * rstd * g3.w + b3.w;

  float qq = y0.x * y0.x + y0.y * y0.y + y0.z * y0.z + y0.w * y0.w +
             y1.x * y1.x + y1.y * y1.y + y1.z * y1.z + y1.w * y1.w +
             y2.x * y2.x + y2.y * y2.y + y2.z * y2.z + y2.w * y2.w +
             y3.x * y3.x + y3.y * y3.y + y3.z * y3.z + y3.w * y3.w;
  qq = wred16(qq);

  // 8 partial dots over this lane's 16 dims
  float dot[8];
#pragma unroll
  for (int j = 0; j < 8; j++) {
    const float* pj = &prS[s * 132 + j * 16];
    const float4 pa = *(const float4*)(pj);
    const float4 pb = *(const float4*)(pj + 4);
    const float4 pc = *(const float4*)(pj + 8);
    const float4 pd = *(const float4*)(pj + 12);
    dot[j] = y0.x * pa.x + y0.y * pa.y + y0.z * pa.z + y0.w * pa.w +
             y1.x * pb.x + y1.y * pb.y + y1.z * pb.z + y1.w * pb.w +
             y2.x * pc.x + y2.y * pc.y + y2.z * pc.z + y2.w * pc.w +
             y3.x * pd.x + y3.y * pd.y + y3.z * pd.z + y3.w * pd.w;
  }
  // octet butterfly on all 8 values (serves all 4 pixels at once)
#pragma unroll
  for (int o = 1; o <= 4; o <<= 1) {
#pragma unroll
    for (int j = 0; j < 8; j++) dot[j] += __shfl_xor(dot[j], o, 64);
  }
  // transpose: lane picks dot[s&7], then one xor-8 completes the 16-lane sum
  int bsel = s & 7;
  float t0 = (bsel & 1) ? dot[1] : dot[0];
  float t1 = (bsel & 1) ? dot[3] : dot[2];
  float t2 = (bsel & 1) ? dot[5] : dot[4];
  float t3 = (bsel & 1) ? dot[7] : dot[6];
  float u0 = (bsel & 2) ? t1 : t0;
  float u1v = (bsel & 2) ? t3 : t2;
  float v = (bsel & 4) ? u1v : u0;
  v += __shfl_xor(v, 8, 64);

  float inv = 1.0f / fmaxf(sqrtf(qq), 1e-12f);
  float d = v * inv;   // lane s (and s+8) holds final dot j = s&7, j = 2k+m

  if (s < 8) out_logits[(size_t)n * 8 + ((s & 1) << 2) + (s >> 1)] = d;

  // nearest: nr_k = max over m; lanes 2k,2k+1 both end with nr_k
  float nm = fmaxf(d, __shfl_xor(d, 1, 64));
  // LN over the 4 classes (lanes differing in bits 1,2)
  float tA = __shfl_xor(nm, 2, 64);
  float s2 = nm + tA, q2 = nm * nm + tA * tA;
  float s4 = s2 + __shfl_xor(s2, 4, 64);
  float q4 = q2 + __shfl_xor(q2, 4, 64);
  float m4 = 0.25f * s4;
  float v4 = 0.25f * q4 - m4 * m4;
  float rs4 = rsqrtf(v4 + LN_EPS);
  int k = (s >> 1) & 3;
  float lnv = (nm - m4) * rs4 * mng[k] + mnb[k];

  int bimg = n / HWIMG;
  int p = n - bimg * HWIMG;
  if (s < 8 && (s & 1) == 0)
    out_nearest[((size_t)bimg * 4 + k) * HWIMG + p] = lnv;

  // argmax over k with tie -> lowest k
  float av = lnv; int ak = k;
#pragma unroll
  for (int o = 2; o <= 4; o <<= 1) {
    float ov = __shfl_xor(av, o, 64);
    int ok = __shfl_xor(ak, o, 64);
    bool take = (ov > av) || (ov == av && ok < ak);
    av = take ? ov : av;
    ak = take ? ok : ak;
  }
  if (s == 0) ws->flags[n] = (lab == ak) ? (unsigned char)1 : (unsigned char)0;
}

// ---------------- K2: sinkhorn reduction pass (iter = 1..3) ----------------
// u-chain recomputed per block from R (identical float ops to the old k_u)
template <int ITER>
__global__ __launch_bounds__(256) void k_sink(const float* __restrict__ logits,
                                              const int* __restrict__ label,
                                              Ws* __restrict__ ws) {
  __shared__ float su1[8], su2[8], sBn[4];
  int tid = threadIdx.x;
  if (ITER >= 2) {
    if (tid < 8) {
      int c = tid >> 1;
      float S = (float)ws->R[0][c * 2] + (float)ws->R[0][c * 2 + 1];
      float uu0 = 1.0f / fmaxf(S, 1e-30f);
      float R0 = (float)ws->R[0][tid];
      float uu1 = uu0 / (fmaxf(uu0 * R0, 1e-30f) * 2.0f);
      su1[tid] = uu1;
      if (ITER >= 3) {
        float R1 = (float)ws->R[1][tid];
        su2[tid] = uu1 / (fmaxf(uu1 * R1, 1e-30f) * 2.0f);
      }
    }
    if (tid < 4) sBn[tid] = fmaxf((float)ws->cnt4[tid], 1.0f);
  }
  __syncthreads();

  double a0 = 0, a1 = 0, a2 = 0, a3 = 0, a4 = 0, a5 = 0, a6 = 0, a7 = 0;
  unsigned c0 = 0, c1 = 0, c2 = 0, c3 = 0;
  int gtid = blockIdx.x * 256 + tid;
  int T = gridDim.x * 256;
  for (int n = gtid; n < N_PIX; n += T) {
    int c = label[n];
    const float4 la = *(const float4*)(logits + (size_t)n * 8);
    const float4 lb = *(const float4*)(logits + (size_t)n * 8 + 4);
    float s0 = (c & 2) ? ((c & 1) ? la.w : la.z) : ((c & 1) ? la.y : la.x);
    float s1 = (c & 2) ? ((c & 1) ? lb.w : lb.z) : ((c & 1) ? lb.y : lb.x);
    float E0 = expf(s0 / 0.05f);
    float E1 = expf(s1 / 0.05f);
    float v = 1.0f;
    if (ITER >= 2) {
      float S1 = su1[c * 2] * E0 + su1[c * 2 + 1] * E1;
      float v1 = 1.0f / (fmaxf(S1, 1e-30f) * sBn[c]);
      v = v1;
      if (ITER >= 3) {
        float S2 = su2[c * 2] * E0 + su2[c * 2 + 1] * E1;
        v = v1 / (fmaxf(v1 * S2, 1e-30f) * sBn[c]);
      }
    }
    double t0 = (double)(v * E0), t1 = (double)(v * E1);
    if (c == 0) { a0 += t0; a1 += t1; c0++; }
    else if (c == 1) { a2 += t0; a3 += t1; c1++; }
    else if (c == 2) { a4 += t0; a5 += t1; c2++; }
    else { a6 += t0; a7 += t1; c3++; }
  }
  a0 = wredd(a0); a1 = wredd(a1); a2 = wredd(a2); a3 = wredd(a3);
  a4 = wredd(a4); a5 = wredd(a5); a6 = wredd(a6); a7 = wredd(a7);
  __shared__ double lds[4][8];
  __shared__ unsigned ldc[4][4];
  int wave = tid >> 6, lane = tid & 63;
  if (ITER == 1) { c0 = wredu(c0); c1 = wredu(c1); c2 = wredu(c2); c3 = wredu(c3); }
  if (lane == 0) {
    lds[wave][0] = a0; lds[wave][1] = a1; lds[wave][2] = a2; lds[wave][3] = a3;
    lds[wave][4] = a4; lds[wave][5] = a5; lds[wave][6] = a6; lds[wave][7] = a7;
    if (ITER == 1) { ldc[wave][0] = c0; ldc[wave][1] = c1; ldc[wave][2] = c2; ldc[wave][3] = c3; }
  }
  __syncthreads();
  if (tid < 8) {
    double ssum = lds[0][tid] + lds[1][tid] + lds[2][tid] + lds[3][tid];
    unsafeAtomicAdd(&ws->R[ITER - 1][tid], ssum);
  }
  if (ITER == 1 && tid < 4) {
    unsigned cs = ldc[0][tid] + ldc[1][tid] + ldc[2][tid] + ldc[3][tid];
    atomicAdd(&ws->cnt4[tid], cs);
  }
}

// ---------------- K3: proto_target + f / count accumulation ----------------
__global__ __launch_bounds__(256) void k_accum(
    const float* __restrict__ X, const int* __restrict__ label,
    const float* __restrict__ fng, const float* __restrict__ fnb,
    const float* __restrict__ logits, Ws* __restrict__ ws,
    float* __restrict__ out_target) {
  __shared__ float fa[4 * 2048];  // per-wave f accumulator copies (32 KB)
  __shared__ float su[8];
  __shared__ unsigned ldc[4][8];
  int tid = threadIdx.x;
  if (tid < 8) {
    int c = tid >> 1;
    float S = (float)ws->R[0][c * 2] + (float)ws->R[0][c * 2 + 1];
    float uu0 = 1.0f / fmaxf(S, 1e-30f);
    float R0 = (float)ws->R[0][tid];
    float uu1 = uu0 / (fmaxf(uu0 * R0, 1e-30f) * 2.0f);
    float R1 = (float)ws->R[1][tid];
    float uu2 = uu1 / (fmaxf(uu1 * R1, 1e-30f) * 2.0f);
    float R2 = (float)ws->R[2][tid];
    su[tid] = uu2 / (fmaxf(uu2 * R2, 1e-30f) * 2.0f);
  }
  for (int i = tid; i < 4 * 2048; i += 256) fa[i] = 0.f;
  __syncthreads();

  int wave = tid >> 6, lane = tid & 63;
  const float4 g4 = *(const float4*)(fng + lane * 4);
  const float4 b4 = *(const float4*)(fnb + lane * 4);
  float* myAcc = &fa[wave * 2048];

  unsigned cl[8] = {0, 0, 0, 0, 0, 0, 0, 0};
  int gw = blockIdx.x * 4 + wave;
  int GW = gridDim.x * 4;
  for (int ch = gw; ch < N_PIX / 64; ch += GW) {
    int n = ch * 64 + lane;
    int c = label[n];
    int fl = ws->flags[n];
    float s0 = logits[(size_t)n * 8 + c];
    float s1 = logits[(size_t)n * 8 + 4 + c];
    float E0 = expf(s0 / 0.05f);
    float E1 = expf(s1 / 0.05f);
    int idx = (su[c * 2 + 1] * E1 > su[c * 2] * E0) ? 1 : 0;
    out_target[n] = (float)(idx + 2 * c);
    int bucket = c * 2 + idx;
#pragma unroll
    for (int j = 0; j < 8; j++) cl[j] += (fl && bucket == j) ? 1u : 0u;

    unsigned long long mask = __ballot(fl);
    while (mask) {
      int src = __builtin_ctzll(mask);
      mask &= (mask - 1);
      int cc = __shfl(c, src, 64);
      int ii = __shfl(idx, src, 64);
      int nn = ch * 64 + src;
      const float4 x = *(const float4*)(X + (size_t)nn * 256 + lane * 4);
      float s = x.x + x.y + x.z + x.w;
      float q = x.x * x.x + x.y * x.y + x.z * x.z + x.w * x.w;
      s = wredf(s); q = wredf(q);
      float mu = s * (1.0f / 256.0f);
      float var = q * (1.0f / 256.0f) - mu * mu;
      float rstd = rsqrtf(var + LN_EPS);
      float y0 = (x.x - mu) * rstd * g4.x + b4.x;
      float y1 = (x.y - mu) * rstd * g4.y + b4.y;
      float y2 = (x.z - mu) * rstd * g4.z + b4.z;
      float y3 = (x.w - mu) * rstd * g4.w + b4.w;
      float qq = y0 * y0 + y1 * y1 + y2 * y2 + y3 * y3;
      qq = wredf(qq);
      float inv = 1.0f / fmaxf(sqrtf(qq), 1e-12f);
      float* dst = myAcc + (cc * 2 + ii) * 256 + lane * 4;
      dst[0] += y0 * inv; dst[1] += y1 * inv; dst[2] += y2 * inv; dst[3] += y3 * inv;
    }
  }
#pragma unroll
  for (int j = 0; j < 8; j++) cl[j] = wredu(cl[j]);
  if (lane == 0) {
#pragma unroll
    for (int j = 0; j < 8; j++) ldc[wave][j] = cl[j];
  }
  __syncthreads();
  float* fg = &ws->fAcc[0][0];
  for (int i = tid; i < 2048; i += 256) {
    float ssum = fa[i] + fa[2048 + i] + fa[4096 + i] + fa[6144 + i];
    unsafeAtomicAdd(fg + i, ssum);
  }
  if (tid < 8) {
    unsigned cs = ldc[0][tid] + ldc[1][tid] + ldc[2][tid] + ldc[3][tid];
    if (cs) atomicAdd(&ws->nmk[tid], cs);
  }
}

// ---------------- K4: finalize prototypes ----------------
__global__ __launch_bounds__(512) void k_final(Ws* __restrict__ ws, float* __restrict__ out_protos) {
  int tid = threadIdx.x;
  int r = tid >> 6, lane = tid & 63;
  const float4 f = *(const float4*)(&ws->fAcc[r][lane * 4]);
  float ss = wredf(f.x * f.x + f.y * f.y + f.z * f.z + f.w * f.w);
  float invf = 1.0f / fmaxf(sqrtf(ss), 1e-12f);
  unsigned nr = ws->nmk[r];
  int c = r >> 1;
  unsigned tot = ws->nmk[c * 2] + ws->nmk[c * 2 + 1];
  bool cond = (tot > 0u) && (nr != 0u);
  const float4 p = *(const float4*)(&ws->protoN[r][lane * 4]);
  float u0 = cond ? 0.999f * p.x + 0.001f * (f.x * invf) : p.x;
  float u1 = cond ? 0.999f * p.y + 0.001f * (f.y * invf) : p.y;
  float u2 = cond ? 0.999f * p.z + 0.001f * (f.z * invf) : p.z;
  float u3 = cond ? 0.999f * p.w + 0.001f * (f.w * invf) : p.w;
  float ss2 = wredf(u0 * u0 + u1 * u1 + u2 * u2 + u3 * u3);
  float invn = 1.0f / fmaxf(sqrtf(ss2), 1e-12f);
  float4 o; o.x = u0 * invn; o.y = u1 * invn; o.z = u2 * invn; o.w = u3 * invn;
  *(float4*)(out_protos + r * 256 + lane * 4) = o;
}

// ---------------- launch ----------------
extern "C" void kernel_launch(void* const* d_in, const int* in_sizes, int n_in,
                              void* d_out, int out_size, void* d_ws, size_t ws_size,
                              hipStream_t stream) {
  const float* X = (const float*)d_in[0];
  const int* label = (const int*)d_in[1];
  const float* protos = (const float*)d_in[2];
  const float* fng = (const float*)d_in[3];
  const float* fnb = (const float*)d_in[4];
  const float* mng = (const float*)d_in[5];
  const float* mnb = (const float*)d_in[6];

  float* out = (float*)d_out;
  float* out_nearest = out;                        // 32*4*12544 = 1605632
  float* out_logits = out + 1605632;               // N*8 = 3211264
  float* out_target = out_logits + 3211264;        // N
  float* out_protos = out_target + N_PIX;          // 2048
  Ws* ws = (Ws*)d_ws;

  k_main<<<N_PIX / 16, 256, 0, stream>>>(X, label, protos, fng, fnb, mng, mnb, ws, out_nearest, out_logits);
  k_sink<1><<<512, 256, 0, stream>>>(out_logits, label, ws);
  k_sink<2><<<512, 256, 0, stream>>>(out_logits, label, ws);
  k_sink<3><<<512, 256, 0, stream>>>(out_logits, label, ws);
  k_accum<<<512, 256, 0, stream>>>(X, label, fng, fnb, out_logits, ws, out_target);
  k_final<<<1, 512, 0, stream>>>(ws, out_protos);
}